// Round 12
// baseline (214.588 us; speedup 1.0000x reference)
//
#include <hip/hip_runtime.h>
#include <hip/hip_bf16.h>

// Problem constants
#define BS_   32
#define LQ_   300
#define LV_   13294
#define EMBED_ 256
#define HEADS_ 8
#define HEAD_DIM_ 32
#define NCHUNK16_ 26588  /* 425408 rows / 16 rows per chunk */
#define PSTRIDE_ 512     /* persistent grid size */

typedef __attribute__((ext_vector_type(8))) short bf16x8;
typedef __attribute__((ext_vector_type(4))) float f32x4;

__device__ inline short f2bf(float f) {   // RNE fp32->bf16 (bit trick)
  union { float f; unsigned u; } x; x.f = f;
  return (short)((x.u + 0x7FFF + ((x.u >> 16) & 1)) >> 16);
}
__device__ inline short f2bf_i(float f) { // via HW cvt
  union { __hip_bfloat16 h; short s; } u;
  u.h = __float2bfloat16(f);
  return u.s;
}
__device__ inline float bf2f(short s) {
  union { unsigned u; float f; } x; x.u = ((unsigned)(unsigned short)s) << 16;
  return x.f;
}

// async global->LDS, 16B per lane. LDS dest = wave-uniform base + lane*16.
__device__ __forceinline__ void gld_lds16(const void* g, void* l) {
  __builtin_amdgcn_global_load_lds(
      (const __attribute__((address_space(1))) unsigned int*)g,
      (__attribute__((address_space(3))) unsigned int*)l, 16, 0, 0);
}

// ---------------------------------------------------------------------------
// One up-front transpose+convert for ALL weights (dedicated ws slots).
// ---------------------------------------------------------------------------
__global__ void convert_all(const float* __restrict__ W_off,
                            const float* __restrict__ W_attn,
                            const float* __restrict__ W_val,
                            const float* __restrict__ W_out,
                            short* __restrict__ WtQ,
                            short* __restrict__ WtV,
                            short* __restrict__ WtO) {
  const int n = blockIdx.x;
  const int k = threadIdx.x;
  if (n < 384) {
    WtQ[n * 256 + k] = (n < 256) ? f2bf(W_off[k * 256 + n])
                                 : f2bf(W_attn[k * 128 + (n - 256)]);
  } else if (n < 640) {
    WtV[(n - 384) * 256 + k] = f2bf(W_val[k * 256 + (n - 384)]);
  } else {
    WtO[(n - 640) * 256 + k] = f2bf(W_out[k * 256 + (n - 640)]);
  }
}

// ---------------------------------------------------------------------------
// Mega GEMM: 512 blocks x 512 thr (8 waves), launch_bounds(512,2).
// Phase 1 (blocks 0..149): merged query projection tile (unchanged, R11).
// Phase 2 (ALL blocks): persistent value GEMM, now with a 2-DEEP chunk
//   pipeline: 16-row chunks, 4 x 16 KB LDS ring, stage issued TWO
//   iterations ahead; per-iteration s_waitcnt targets the stage issued 2
//   iterations ago (hiding window = 2 HBM-paced iterations >> latency).
//   Exact per-wave vmcnt (stage=2 ops, stores=8 ops):
//     it0: newer-than-stage(0) = st(1)2+st(2)2            -> vmcnt(4)
//     it1: newer = st(2)2+stores(0)8+st(3)2               -> vmcnt(12)
//     steady: stores(i-2)8+st(i+1)2+stores(i-1)8+st(i+2)2 -> vmcnt(20)
//     tails (no st(i+2) / also no st(i+1))                -> 18 / 16
//   WAR: buf (it+2)&3 was read at it-2, done 2 barriers ago. RAW: own
//   vmcnt + barrier => all waves' stage(i) retired before compute(i).
// ---------------------------------------------------------------------------
__global__ __launch_bounds__(512, 2) void mega_gemm(
    const float* __restrict__ value, const short* __restrict__ WtV,
    const float* __restrict__ b_val, short* __restrict__ Vp,
    const float* __restrict__ query, const short* __restrict__ WtQ,
    const float* __restrict__ b_off, const float* __restrict__ b_attn,
    float* __restrict__ offs, float* __restrict__ logits) {
  __shared__ float As[16384];   // 64 KB: phase1 = 64x256; phase2 = 4 x 4096

  const int tid = threadIdx.x;
  const int lane = tid & 63;
  const int w = tid >> 6;        // wave 0..7
  const int lr = lane & 15;
  const int lkq = lane >> 4;     // k-quarter
  const int bid = blockIdx.x;

  // ================= phase 1: query projection (blocks 0..149) ============
  if (bid < 150) {
    const size_t m0 = (size_t)bid * 64;
#pragma unroll
    for (int i = 0; i < 8; ++i) {
      const int row = w * 8 + i;
      gld_lds16(query + (m0 + row) * 256 + ((lane ^ (row & 7)) * 4), As + row * 256);
    }
    __syncthreads();   // drains vmcnt(0) + barrier

    if (w < 6) {
      const int n0 = w * 64;
      f32x4 acc[4][4];
#pragma unroll
      for (int i = 0; i < 4; ++i)
#pragma unroll
        for (int jj = 0; jj < 4; ++jj) acc[i][jj] = (f32x4){0.f, 0.f, 0.f, 0.f};

#pragma unroll
      for (int kt = 0; kt < 8; ++kt) {
        bf16x8 bfr[4];
#pragma unroll
        for (int nf = 0; nf < 4; ++nf)
          bfr[nf] = *(const bf16x8*)(WtQ + (size_t)(n0 + nf * 16 + lr) * 256 + kt * 32 + lkq * 8);
#pragma unroll
        for (int mf = 0; mf < 4; ++mf) {
          const int row = mf * 16 + lr;
          const int g = kt * 8 + lkq * 2;
          const f32x4 a0 = *(const f32x4*)(As + row * 256 + (((g    ) ^ (row & 7)) * 4));
          const f32x4 a1 = *(const f32x4*)(As + row * 256 + (((g + 1) ^ (row & 7)) * 4));
          bf16x8 af;
#pragma unroll
          for (int i = 0; i < 4; ++i) {
            af[i]     = f2bf_i(a0[i]);
            af[i + 4] = f2bf_i(a1[i]);
          }
#pragma unroll
          for (int nf = 0; nf < 4; ++nf)
            acc[mf][nf] = __builtin_amdgcn_mfma_f32_16x16x32_bf16(af, bfr[nf], acc[mf][nf], 0, 0, 0);
        }
      }

      float bv[4];
#pragma unroll
      for (int nf = 0; nf < 4; ++nf) {
        const int n = n0 + nf * 16 + lr;
        bv[nf] = (n < 256) ? b_off[n] : b_attn[n - 256];
      }
      const int lq4 = lkq * 4;
#pragma unroll
      for (int mf = 0; mf < 4; ++mf)
#pragma unroll
        for (int r = 0; r < 4; ++r) {
          const size_t m = m0 + mf * 16 + lq4 + r;
#pragma unroll
          for (int nf = 0; nf < 4; ++nf) {
            const int n = n0 + nf * 16 + lr;
            const float v = acc[mf][nf][r] + bv[nf];
            if (n < 256) offs[m * 256 + n] = v;
            else         logits[m * 128 + (n - 256)] = v;
          }
        }
    }
    __syncthreads();   // all waves done with As before phase 2 overwrites it
  }

  // ================= phase 2: persistent value GEMM (all blocks) ==========
  bf16x8 bfr[2][8];
#pragma unroll
  for (int nf = 0; nf < 2; ++nf) {
    const size_t bbase = (size_t)(w * 32 + nf * 16 + lr) * 256 + lkq * 8;
#pragma unroll
    for (int kt = 0; kt < 8; ++kt)
      bfr[nf][kt] = *(const bf16x8*)(WtV + bbase + kt * 32);
  }
  float bv0 = b_val[w * 32 + lr];
  float bv1 = b_val[w * 32 + 16 + lr];

  // stage one 16-row chunk (16 KB): 2 rows per wave, 1 KB per instr
  auto stage16 = [&](int buf, int c) {
    const float* src = value + (size_t)c * (16 * 256);
#pragma unroll
    for (int i = 0; i < 2; ++i) {
      const int r = w * 2 + i;
      gld_lds16(src + r * 256 + ((lane ^ (r & 7)) * 4), As + buf * 4096 + r * 256);
    }
  };

  const int c0 = bid;
  stage16(0, c0);
  stage16(1, c0 + PSTRIDE_);          // every block has >= 51 chunks

  int it = 0;
  for (int c = c0; c < NCHUNK16_; c += PSTRIDE_, ++it) {
    const bool s1 = (c + PSTRIDE_ < NCHUNK16_);       // stage(i+1) was issued
    const bool s2 = (c + 2 * PSTRIDE_ < NCHUNK16_);   // stage(i+2) issued now
    if (s2) stage16((it + 2) & 3, c + 2 * PSTRIDE_);

    if (it == 0)      asm volatile("s_waitcnt vmcnt(4)" ::: "memory");
    else if (it == 1) asm volatile("s_waitcnt vmcnt(12)" ::: "memory");
    else if (s2)      asm volatile("s_waitcnt vmcnt(20)" ::: "memory");
    else if (s1)      asm volatile("s_waitcnt vmcnt(18)" ::: "memory");
    else              asm volatile("s_waitcnt vmcnt(16)" ::: "memory");
    asm volatile("s_barrier" ::: "memory");

    // ---- compute chunk c from As[it&3]: 1 m-frag x 2 n-frags ----
    f32x4 acc0 = (f32x4){0.f, 0.f, 0.f, 0.f};
    f32x4 acc1 = (f32x4){0.f, 0.f, 0.f, 0.f};
    const float* as = As + (it & 3) * 4096;
#pragma unroll
    for (int kt = 0; kt < 8; ++kt) {
      const int g = kt * 8 + lkq * 2;
      const f32x4 a0 = *(const f32x4*)(as + lr * 256 + (((g    ) ^ (lr & 7)) * 4));
      const f32x4 a1 = *(const f32x4*)(as + lr * 256 + (((g + 1) ^ (lr & 7)) * 4));
      bf16x8 af;
#pragma unroll
      for (int i = 0; i < 4; ++i) {
        af[i]     = f2bf_i(a0[i]);
        af[i + 4] = f2bf_i(a1[i]);
      }
      acc0 = __builtin_amdgcn_mfma_f32_16x16x32_bf16(af, bfr[0][kt], acc0, 0, 0, 0);
      acc1 = __builtin_amdgcn_mfma_f32_16x16x32_bf16(af, bfr[1][kt], acc1, 0, 0, 0);
    }

    // ---- store chunk c (8 scalar bf16 stores; D map col=lr, row=lkq*4+rr) ----
#pragma unroll
    for (int rr = 0; rr < 4; ++rr) {
      const unsigned m = (unsigned)c * 16 + lkq * 4 + rr;
      const unsigned b_ = m / LV_;
      const unsigned pos = m - b_ * LV_;
      const size_t rowbase = ((size_t)(b_ * HEADS_ + w) * LV_ + pos) * HEAD_DIM_;
      Vp[rowbase + lr]      = f2bf(acc0[rr] + bv0);
      Vp[rowbase + 16 + lr] = f2bf(acc1[rr] + bv1);
    }
  }
}

// ---------------------------------------------------------------------------
// Final output projection (R6 bigA structure, f32 out).
// ---------------------------------------------------------------------------
__global__ __launch_bounds__(256, 2) void gemm_qproj(
    const float* __restrict__ A, const short* __restrict__ Wt,
    const float* __restrict__ bias, float* __restrict__ C) {
  __shared__ float As[64 * 256];

  const int tid = threadIdx.x;
  const int lane = tid & 63;
  const int w = tid >> 6;
  const int n0 = w * 64;
  const size_t m0 = (size_t)blockIdx.x * 64;
  const int lr = lane & 15;
  const int lkq = lane >> 4;

#pragma unroll
  for (int i = 0; i < 16; ++i) {
    const int row = w * 16 + i;
    gld_lds16(A + (m0 + row) * 256 + ((lane ^ (row & 7)) * 4), As + row * 256);
  }

  bf16x8 bfr[4][8];
#pragma unroll
  for (int nf = 0; nf < 4; ++nf) {
    const size_t bbase = (size_t)(n0 + nf * 16 + lr) * 256 + lkq * 8;
#pragma unroll
    for (int kt = 0; kt < 8; ++kt)
      bfr[nf][kt] = *(const bf16x8*)(Wt + bbase + kt * 32);
  }

  f32x4 acc[4][4];
#pragma unroll
  for (int i = 0; i < 4; ++i)
#pragma unroll
    for (int jj = 0; jj < 4; ++jj) acc[i][jj] = (f32x4){0.f, 0.f, 0.f, 0.f};

  __syncthreads();

#pragma unroll
  for (int kt = 0; kt < 8; ++kt) {
#pragma unroll
    for (int mf = 0; mf < 4; ++mf) {
      const int row = mf * 16 + lr;
      const int gbase = kt * 8 + lkq * 2;
      const f32x4 a0 = *(const f32x4*)(As + row * 256 + ((gbase) ^ (row & 7)) * 4);
      const f32x4 a1 = *(const f32x4*)(As + row * 256 + ((gbase + 1) ^ (row & 7)) * 4);
      bf16x8 af;
#pragma unroll
      for (int i = 0; i < 4; ++i) {
        af[i]     = f2bf_i(a0[i]);
        af[i + 4] = f2bf_i(a1[i]);
      }
#pragma unroll
      for (int nf = 0; nf < 4; ++nf)
        acc[mf][nf] = __builtin_amdgcn_mfma_f32_16x16x32_bf16(af, bfr[nf][kt], acc[mf][nf], 0, 0, 0);
    }
  }

  float bv[4];
#pragma unroll
  for (int nf = 0; nf < 4; ++nf) bv[nf] = bias[n0 + nf * 16 + lr];
  const int lq4 = lkq * 4;
#pragma unroll
  for (int mf = 0; mf < 4; ++mf)
#pragma unroll
    for (int r = 0; r < 4; ++r) {
      const size_t m = m0 + mf * 16 + lq4 + r;
#pragma unroll
      for (int nf = 0; nf < 4; ++nf) {
        const int n = n0 + nf * 16 + lr;
        C[m * 256 + n] = acc[mf][nf][r] + bv[nf];
      }
    }
}

// ---------------------------------------------------------------------------
// Fused softmax + deformable sampling, 8-channel threads (max TLP).
// ---------------------------------------------------------------------------
__global__ __launch_bounds__(256) void msda_sample_fused(
    const float* __restrict__ ref_pts,   // [BS*LQ, 4, 2]
    const float* __restrict__ offsets,   // [BS*LQ, 256]  (h,l,p,2)
    const float* __restrict__ logits,    // [BS*LQ, 128]  (h,l,p)
    const short* __restrict__ value_p,   // [b,h,pos,32] bf16
    float* __restrict__ tmp)             // [BS*LQ, 256]
{
  const int t = blockIdx.x * 256 + threadIdx.x;
  const int c8 = t & 3;
  const int h = (t >> 2) & 7;
  const int row = t >> 5;
  const int b = row / LQ_;

  const int HS[4] = {100, 50, 25, 13};
  const int START[4] = {0, 10000, 12500, 13125};

  // ---- softmax over 16 logits, in-register ----
  const float* lg = logits + (size_t)row * 128 + h * 16;
  float wv[16];
  float mx = -1e30f;
#pragma unroll
  for (int i = 0; i < 4; ++i) {
    const f32x4 v = *(const f32x4*)(lg + i * 4);
#pragma unroll
    for (int jj = 0; jj < 4; ++jj) { wv[i * 4 + jj] = v[jj]; mx = fmaxf(mx, v[jj]); }
  }
  float sum = 0.f;
#pragma unroll
  for (int i = 0; i < 16; ++i) { wv[i] = __expf(wv[i] - mx); sum += wv[i]; }
  const float inv = 1.0f / sum;
#pragma unroll
  for (int i = 0; i < 16; ++i) wv[i] *= inv;

  const float* offr = offsets + (size_t)row * 256 + h * 32;
  const float* refr = ref_pts + (size_t)row * 8;

  float acc[8];
#pragma unroll
  for (int jj = 0; jj < 8; ++jj) acc[jj] = 0.f;

#pragma unroll
  for (int l = 0; l < 4; ++l) {
    const int HH = HS[l];
    const int WW = HS[l];
    const float fH = (float)HH, fW = (float)WW;
    const float rx = refr[l * 2 + 0];
    const float ry = refr[l * 2 + 1];
    const short* vbase =
        value_p + ((size_t)(b * HEADS_ + h) * LV_ + START[l]) * HEAD_DIM_ + c8 * 8;
#pragma unroll
    for (int p = 0; p < 4; ++p) {
      const float ox = offr[(l * 4 + p) * 2 + 0];
      const float oy = offr[(l * 4 + p) * 2 + 1];
      const float x = (rx + ox / fW) * fW - 0.5f;
      const float y = (ry + oy / fH) * fH - 0.5f;
      const float x0f = floorf(x), y0f = floorf(y);
      const float fx = x - x0f, fy = y - y0f;
      const int x0 = (int)x0f, y0 = (int)y0f;
      const float wgt = wv[l * 4 + p];
      const float iy0 = (y0 >= 0 && y0 < HH) ? 1.f : 0.f;
      const float iy1 = (y0 + 1 >= 0 && y0 + 1 < HH) ? 1.f : 0.f;
      const float ix0 = (x0 >= 0 && x0 < WW) ? 1.f : 0.f;
      const float ix1 = (x0 + 1 >= 0 && x0 + 1 < WW) ? 1.f : 0.f;
      const float w00 = (1.f - fy) * (1.f - fx) * wgt * iy0 * ix0;
      const float w01 = (1.f - fy) * fx * wgt * iy0 * ix1;
      const float w10 = fy * (1.f - fx) * wgt * iy1 * ix0;
      const float w11 = fy * fx * wgt * iy1 * ix1;
      const int xc0 = min(max(x0, 0), WW - 1);
      const int xc1 = min(max(x0 + 1, 0), WW - 1);
      const int yc0 = min(max(y0, 0), HH - 1);
      const int yc1 = min(max(y0 + 1, 0), HH - 1);
      const bf16x8 q00 = *(const bf16x8*)(vbase + (size_t)(yc0 * WW + xc0) * HEAD_DIM_);
      const bf16x8 q01 = *(const bf16x8*)(vbase + (size_t)(yc0 * WW + xc1) * HEAD_DIM_);
      const bf16x8 q10 = *(const bf16x8*)(vbase + (size_t)(yc1 * WW + xc0) * HEAD_DIM_);
      const bf16x8 q11 = *(const bf16x8*)(vbase + (size_t)(yc1 * WW + xc1) * HEAD_DIM_);
#pragma unroll
      for (int jj = 0; jj < 8; ++jj) {
        acc[jj] += w00 * bf2f(q00[jj]) + w01 * bf2f(q01[jj]) +
                   w10 * bf2f(q10[jj]) + w11 * bf2f(q11[jj]);
      }
    }
  }
  float* o = tmp + (size_t)row * 256 + h * 32 + c8 * 8;
  f32x4 o0 = {acc[0], acc[1], acc[2], acc[3]};
  f32x4 o1 = {acc[4], acc[5], acc[6], acc[7]};
  *(f32x4*)(o) = o0;
  *(f32x4*)(o + 4) = o1;
}

// ---------------------------------------------------------------------------
extern "C" void kernel_launch(void* const* d_in, const int* in_sizes, int n_in,
                              void* d_out, int out_size, void* d_ws, size_t ws_size,
                              hipStream_t stream) {
  const float* query  = (const float*)d_in[0];
  const float* refpts = (const float*)d_in[1];
  const float* value  = (const float*)d_in[2];
  const float* W_off  = (const float*)d_in[4];
  const float* b_off  = (const float*)d_in[5];
  const float* W_attn = (const float*)d_in[6];
  const float* b_attn = (const float*)d_in[7];
  const float* W_val  = (const float*)d_in[8];
  const float* b_val  = (const float*)d_in[9];
  const float* W_out  = (const float*)d_in[10];
  const float* b_out  = (const float*)d_in[11];
  float* out = (float*)d_out;

  // Dedicated workspace slots -- no aliasing. Total 242.7 MB.
  char* ws = (char*)d_ws;
  short* value_p = (short*)ws;                                 // 217,710,592 B
  size_t off = (size_t)BS_ * HEADS_ * LV_ * HEAD_DIM_ * 2;
  float* offsets = (float*)(ws + off); off += (size_t)BS_ * LQ_ * 256 * 4;  // 9.83 MB
  float* logits  = (float*)(ws + off); off += (size_t)BS_ * LQ_ * 128 * 4;  // 4.92 MB
  float* tmp     = (float*)(ws + off); off += (size_t)BS_ * LQ_ * 256 * 4;  // 9.83 MB
  short* WtQ = (short*)(ws + off); off += 384 * 256 * 2;                    // 192 KB
  short* WtV = (short*)(ws + off); off += 256 * 256 * 2;                    // 128 KB
  short* WtO = (short*)(ws + off); off += 256 * 256 * 2;                    // 128 KB

  const int MQ = BS_ * LQ_;   // 9600 = 64*150

  convert_all<<<896, 256, 0, stream>>>(W_off, W_attn, W_val, W_out, WtQ, WtV, WtO);
  mega_gemm<<<PSTRIDE_, 512, 0, stream>>>(value, WtV, b_val, value_p,
                                          query, WtQ, b_off, b_attn, offsets, logits);
  msda_sample_fused<<<(MQ * 32) / 256, 256, 0, stream>>>(refpts, offsets, logits, value_p, tmp);
  gemm_qproj<<<MQ / 64, 256, 0, stream>>>(tmp, WtO, b_out, out);
}

// Round 13
// 206.471 us; speedup vs baseline: 1.0393x; 1.0393x over previous
//
#include <hip/hip_runtime.h>
#include <hip/hip_bf16.h>

// Problem constants
#define BS_   32
#define LQ_   300
#define LV_   13294
#define EMBED_ 256
#define HEADS_ 8
#define HEAD_DIM_ 32
#define NCHUNK_ 13294   /* 425408 rows / 32 rows per chunk */
#define PSTRIDE_ 512    /* persistent grid size */

typedef __attribute__((ext_vector_type(8))) short bf16x8;
typedef __attribute__((ext_vector_type(4))) float f32x4;

__device__ inline short f2bf(float f) {   // RNE fp32->bf16 (bit trick)
  union { float f; unsigned u; } x; x.f = f;
  return (short)((x.u + 0x7FFF + ((x.u >> 16) & 1)) >> 16);
}
__device__ inline short f2bf_i(float f) { // via HW cvt
  union { __hip_bfloat16 h; short s; } u;
  u.h = __float2bfloat16(f);
  return u.s;
}
__device__ inline float bf2f(short s) {
  union { unsigned u; float f; } x; x.u = ((unsigned)(unsigned short)s) << 16;
  return x.f;
}

// async global->LDS, 16B per lane. LDS dest = wave-uniform base + lane*16.
__device__ __forceinline__ void gld_lds16(const void* g, void* l) {
  __builtin_amdgcn_global_load_lds(
      (const __attribute__((address_space(1))) unsigned int*)g,
      (__attribute__((address_space(3))) unsigned int*)l, 16, 0, 0);
}

// ---------------------------------------------------------------------------
// One up-front transpose+convert for ALL weights (dedicated ws slots).
// ---------------------------------------------------------------------------
__global__ void convert_all(const float* __restrict__ W_off,
                            const float* __restrict__ W_attn,
                            const float* __restrict__ W_val,
                            const float* __restrict__ W_out,
                            short* __restrict__ WtQ,
                            short* __restrict__ WtV,
                            short* __restrict__ WtO) {
  const int n = blockIdx.x;
  const int k = threadIdx.x;
  if (n < 384) {
    WtQ[n * 256 + k] = (n < 256) ? f2bf(W_off[k * 256 + n])
                                 : f2bf(W_attn[k * 128 + (n - 256)]);
  } else if (n < 640) {
    WtV[(n - 384) * 256 + k] = f2bf(W_val[k * 256 + (n - 384)]);
  } else {
    WtO[(n - 640) * 256 + k] = f2bf(W_out[k * 256 + (n - 640)]);
  }
}

// ---------------------------------------------------------------------------
// Mega GEMM kernel: 512 blocks x 512 thr (8 waves), launch_bounds(512,2).
// Phase 1 (blocks 0..149 only): merged query projection tile
//   [offsets | logits](64 rows) = query_tile @ WtQ^T. A staged in the shared
//   64 KB LDS; B fragments read per-use from L2-resident WtQ (192 KB).
// Phase 2 (ALL 512 blocks): R8's persistent chunk-pipelined value GEMM:
//   Vp = bf16(value @ W_val + b_val), layout [b][h][pos][32];
//   2-deep 32 KB LDS ring in the same 64 KB buffer; counted vmcnt(16).
// (R12's 2-deep 16-row variant regressed: per-chunk fixed costs doubled
//  with no latency win -- this 1-deep 32-row form is the measured optimum.)
// ---------------------------------------------------------------------------
__global__ __launch_bounds__(512, 2) void mega_gemm(
    const float* __restrict__ value, const short* __restrict__ WtV,
    const float* __restrict__ b_val, short* __restrict__ Vp,
    const float* __restrict__ query, const short* __restrict__ WtQ,
    const float* __restrict__ b_off, const float* __restrict__ b_attn,
    float* __restrict__ offs, float* __restrict__ logits) {
  __shared__ float As[16384];   // 64 KB, shared by both phases

  const int tid = threadIdx.x;
  const int lane = tid & 63;
  const int w = tid >> 6;        // wave 0..7
  const int lr = lane & 15;
  const int lkq = lane >> 4;     // k-quarter
  const int bid = blockIdx.x;

  // ================= phase 1: query projection (blocks 0..149) ============
  if (bid < 150) {
    const size_t m0 = (size_t)bid * 64;
    // stage query tile: 8 waves x 8 rows (row = 1 KB per instr)
#pragma unroll
    for (int i = 0; i < 8; ++i) {
      const int row = w * 8 + i;
      gld_lds16(query + (m0 + row) * 256 + ((lane ^ (row & 7)) * 4), As + row * 256);
    }
    __syncthreads();   // drains vmcnt(0) + barrier

    if (w < 6) {
      const int n0 = w * 64;
      f32x4 acc[4][4];
#pragma unroll
      for (int i = 0; i < 4; ++i)
#pragma unroll
        for (int jj = 0; jj < 4; ++jj) acc[i][jj] = (f32x4){0.f, 0.f, 0.f, 0.f};

#pragma unroll
      for (int kt = 0; kt < 8; ++kt) {
        bf16x8 bfr[4];
#pragma unroll
        for (int nf = 0; nf < 4; ++nf)
          bfr[nf] = *(const bf16x8*)(WtQ + (size_t)(n0 + nf * 16 + lr) * 256 + kt * 32 + lkq * 8);
#pragma unroll
        for (int mf = 0; mf < 4; ++mf) {
          const int row = mf * 16 + lr;
          const int g = kt * 8 + lkq * 2;
          const f32x4 a0 = *(const f32x4*)(As + row * 256 + (((g    ) ^ (row & 7)) * 4));
          const f32x4 a1 = *(const f32x4*)(As + row * 256 + (((g + 1) ^ (row & 7)) * 4));
          bf16x8 af;
#pragma unroll
          for (int i = 0; i < 4; ++i) {
            af[i]     = f2bf_i(a0[i]);
            af[i + 4] = f2bf_i(a1[i]);
          }
#pragma unroll
          for (int nf = 0; nf < 4; ++nf)
            acc[mf][nf] = __builtin_amdgcn_mfma_f32_16x16x32_bf16(af, bfr[nf], acc[mf][nf], 0, 0, 0);
        }
      }

      float bv[4];
#pragma unroll
      for (int nf = 0; nf < 4; ++nf) {
        const int n = n0 + nf * 16 + lr;
        bv[nf] = (n < 256) ? b_off[n] : b_attn[n - 256];
      }
      const int lq4 = lkq * 4;
#pragma unroll
      for (int mf = 0; mf < 4; ++mf)
#pragma unroll
        for (int r = 0; r < 4; ++r) {
          const size_t m = m0 + mf * 16 + lq4 + r;
#pragma unroll
          for (int nf = 0; nf < 4; ++nf) {
            const int n = n0 + nf * 16 + lr;
            const float v = acc[mf][nf][r] + bv[nf];
            if (n < 256) offs[m * 256 + n] = v;
            else         logits[m * 128 + (n - 256)] = v;
          }
        }
    }
    __syncthreads();   // all waves done with As before phase 2 overwrites it
  }

  // ================= phase 2: persistent value GEMM (all blocks) ==========
  bf16x8 bfr[2][8];
#pragma unroll
  for (int nf = 0; nf < 2; ++nf) {
    const size_t bbase = (size_t)(w * 32 + nf * 16 + lr) * 256 + lkq * 8;
#pragma unroll
    for (int kt = 0; kt < 8; ++kt)
      bfr[nf][kt] = *(const bf16x8*)(WtV + bbase + kt * 32);
  }
  float bv[2];
#pragma unroll
  for (int nf = 0; nf < 2; ++nf) bv[nf] = b_val[w * 32 + nf * 16 + lr];

  auto stage = [&](int buf, int c) {
    const float* src = value + (size_t)c * (32 * 256);
#pragma unroll
    for (int i = 0; i < 4; ++i) {
      const int r = w * 4 + i;
      gld_lds16(src + r * 256 + ((lane ^ (r & 7)) * 4), As + buf * 8192 + r * 256);
    }
  };

  const int c0 = bid;
  stage(0, c0);
  asm volatile("s_waitcnt vmcnt(0)" ::: "memory");
  __syncthreads();

  int cb = 0;
  for (int c = c0; c < NCHUNK_; c += PSTRIDE_) {
    const int nxt = c + PSTRIDE_;
    if (nxt < NCHUNK_) stage(cb ^ 1, nxt);

    f32x4 acc[2][2];
#pragma unroll
    for (int i = 0; i < 2; ++i)
#pragma unroll
      for (int jj = 0; jj < 2; ++jj) acc[i][jj] = (f32x4){0.f, 0.f, 0.f, 0.f};

    const float* as = As + cb * 8192;
#pragma unroll
    for (int kt = 0; kt < 8; ++kt) {
      const int r0 = lr;
      const int r1 = 16 + lr;
      const int g = kt * 8 + lkq * 2;
      const f32x4 a00 = *(const f32x4*)(as + r0 * 256 + (((g    ) ^ (r0 & 7)) * 4));
      const f32x4 a01 = *(const f32x4*)(as + r0 * 256 + (((g + 1) ^ (r0 & 7)) * 4));
      const f32x4 a10 = *(const f32x4*)(as + r1 * 256 + (((g    ) ^ (r1 & 7)) * 4));
      const f32x4 a11 = *(const f32x4*)(as + r1 * 256 + (((g + 1) ^ (r1 & 7)) * 4));
      bf16x8 af0, af1;
#pragma unroll
      for (int i = 0; i < 4; ++i) {
        af0[i]     = f2bf_i(a00[i]);
        af0[i + 4] = f2bf_i(a01[i]);
        af1[i]     = f2bf_i(a10[i]);
        af1[i + 4] = f2bf_i(a11[i]);
      }
      acc[0][0] = __builtin_amdgcn_mfma_f32_16x16x32_bf16(af0, bfr[0][kt], acc[0][0], 0, 0, 0);
      acc[0][1] = __builtin_amdgcn_mfma_f32_16x16x32_bf16(af0, bfr[1][kt], acc[0][1], 0, 0, 0);
      acc[1][0] = __builtin_amdgcn_mfma_f32_16x16x32_bf16(af1, bfr[0][kt], acc[1][0], 0, 0, 0);
      acc[1][1] = __builtin_amdgcn_mfma_f32_16x16x32_bf16(af1, bfr[1][kt], acc[1][1], 0, 0, 0);
    }

#pragma unroll
    for (int mf = 0; mf < 2; ++mf)
#pragma unroll
      for (int rr = 0; rr < 4; ++rr) {
        const unsigned m = (unsigned)c * 32 + mf * 16 + lkq * 4 + rr;
        const unsigned b_ = m / LV_;
        const unsigned pos = m - b_ * LV_;
        const size_t rowbase = ((size_t)(b_ * HEADS_ + w) * LV_ + pos) * HEAD_DIM_;
#pragma unroll
        for (int nf = 0; nf < 2; ++nf)
          Vp[rowbase + nf * 16 + lr] = f2bf(acc[mf][nf][rr] + bv[nf]);
      }

    if (nxt < NCHUNK_) {
      asm volatile("s_waitcnt vmcnt(16)" ::: "memory");
      asm volatile("s_barrier" ::: "memory");
    }
    cb ^= 1;
  }
}

// ---------------------------------------------------------------------------
// Final output projection (R6 bigA structure, f32 out).
// ---------------------------------------------------------------------------
__global__ __launch_bounds__(256, 2) void gemm_qproj(
    const float* __restrict__ A, const short* __restrict__ Wt,
    const float* __restrict__ bias, float* __restrict__ C) {
  __shared__ float As[64 * 256];

  const int tid = threadIdx.x;
  const int lane = tid & 63;
  const int w = tid >> 6;
  const int n0 = w * 64;
  const size_t m0 = (size_t)blockIdx.x * 64;
  const int lr = lane & 15;
  const int lkq = lane >> 4;

#pragma unroll
  for (int i = 0; i < 16; ++i) {
    const int row = w * 16 + i;
    gld_lds16(A + (m0 + row) * 256 + ((lane ^ (row & 7)) * 4), As + row * 256);
  }

  bf16x8 bfr[4][8];
#pragma unroll
  for (int nf = 0; nf < 4; ++nf) {
    const size_t bbase = (size_t)(n0 + nf * 16 + lr) * 256 + lkq * 8;
#pragma unroll
    for (int kt = 0; kt < 8; ++kt)
      bfr[nf][kt] = *(const bf16x8*)(Wt + bbase + kt * 32);
  }

  f32x4 acc[4][4];
#pragma unroll
  for (int i = 0; i < 4; ++i)
#pragma unroll
    for (int jj = 0; jj < 4; ++jj) acc[i][jj] = (f32x4){0.f, 0.f, 0.f, 0.f};

  __syncthreads();

#pragma unroll
  for (int kt = 0; kt < 8; ++kt) {
#pragma unroll
    for (int mf = 0; mf < 4; ++mf) {
      const int row = mf * 16 + lr;
      const int gbase = kt * 8 + lkq * 2;
      const f32x4 a0 = *(const f32x4*)(As + row * 256 + ((gbase) ^ (row & 7)) * 4);
      const f32x4 a1 = *(const f32x4*)(As + row * 256 + ((gbase + 1) ^ (row & 7)) * 4);
      bf16x8 af;
#pragma unroll
      for (int i = 0; i < 4; ++i) {
        af[i]     = f2bf_i(a0[i]);
        af[i + 4] = f2bf_i(a1[i]);
      }
#pragma unroll
      for (int nf = 0; nf < 4; ++nf)
        acc[mf][nf] = __builtin_amdgcn_mfma_f32_16x16x32_bf16(af, bfr[nf][kt], acc[mf][nf], 0, 0, 0);
    }
  }

  float bv[4];
#pragma unroll
  for (int nf = 0; nf < 4; ++nf) bv[nf] = bias[n0 + nf * 16 + lr];
  const int lq4 = lkq * 4;
#pragma unroll
  for (int mf = 0; mf < 4; ++mf)
#pragma unroll
    for (int r = 0; r < 4; ++r) {
      const size_t m = m0 + mf * 16 + lq4 + r;
#pragma unroll
      for (int nf = 0; nf < 4; ++nf) {
        const int n = n0 + nf * 16 + lr;
        C[m * 256 + n] = acc[mf][nf][r] + bv[nf];
      }
    }
}

// ---------------------------------------------------------------------------
// Fused softmax + deformable sampling, 8-channel threads (max TLP).
// ---------------------------------------------------------------------------
__global__ __launch_bounds__(256) void msda_sample_fused(
    const float* __restrict__ ref_pts,   // [BS*LQ, 4, 2]
    const float* __restrict__ offsets,   // [BS*LQ, 256]  (h,l,p,2)
    const float* __restrict__ logits,    // [BS*LQ, 128]  (h,l,p)
    const short* __restrict__ value_p,   // [b,h,pos,32] bf16
    float* __restrict__ tmp)             // [BS*LQ, 256]
{
  const int t = blockIdx.x * 256 + threadIdx.x;
  const int c8 = t & 3;
  const int h = (t >> 2) & 7;
  const int row = t >> 5;
  const int b = row / LQ_;

  const int HS[4] = {100, 50, 25, 13};
  const int START[4] = {0, 10000, 12500, 13125};

  // ---- softmax over 16 logits, in-register ----
  const float* lg = logits + (size_t)row * 128 + h * 16;
  float wv[16];
  float mx = -1e30f;
#pragma unroll
  for (int i = 0; i < 4; ++i) {
    const f32x4 v = *(const f32x4*)(lg + i * 4);
#pragma unroll
    for (int jj = 0; jj < 4; ++jj) { wv[i * 4 + jj] = v[jj]; mx = fmaxf(mx, v[jj]); }
  }
  float sum = 0.f;
#pragma unroll
  for (int i = 0; i < 16; ++i) { wv[i] = __expf(wv[i] - mx); sum += wv[i]; }
  const float inv = 1.0f / sum;
#pragma unroll
  for (int i = 0; i < 16; ++i) wv[i] *= inv;

  const float* offr = offsets + (size_t)row * 256 + h * 32;
  const float* refr = ref_pts + (size_t)row * 8;

  float acc[8];
#pragma unroll
  for (int jj = 0; jj < 8; ++jj) acc[jj] = 0.f;

#pragma unroll
  for (int l = 0; l < 4; ++l) {
    const int HH = HS[l];
    const int WW = HS[l];
    const float fH = (float)HH, fW = (float)WW;
    const float rx = refr[l * 2 + 0];
    const float ry = refr[l * 2 + 1];
    const short* vbase =
        value_p + ((size_t)(b * HEADS_ + h) * LV_ + START[l]) * HEAD_DIM_ + c8 * 8;
#pragma unroll
    for (int p = 0; p < 4; ++p) {
      const float ox = offr[(l * 4 + p) * 2 + 0];
      const float oy = offr[(l * 4 + p) * 2 + 1];
      const float x = (rx + ox / fW) * fW - 0.5f;
      const float y = (ry + oy / fH) * fH - 0.5f;
      const float x0f = floorf(x), y0f = floorf(y);
      const float fx = x - x0f, fy = y - y0f;
      const int x0 = (int)x0f, y0 = (int)y0f;
      const float wgt = wv[l * 4 + p];
      const float iy0 = (y0 >= 0 && y0 < HH) ? 1.f : 0.f;
      const float iy1 = (y0 + 1 >= 0 && y0 + 1 < HH) ? 1.f : 0.f;
      const float ix0 = (x0 >= 0 && x0 < WW) ? 1.f : 0.f;
      const float ix1 = (x0 + 1 >= 0 && x0 + 1 < WW) ? 1.f : 0.f;
      const float w00 = (1.f - fy) * (1.f - fx) * wgt * iy0 * ix0;
      const float w01 = (1.f - fy) * fx * wgt * iy0 * ix1;
      const float w10 = fy * (1.f - fx) * wgt * iy1 * ix0;
      const float w11 = fy * fx * wgt * iy1 * ix1;
      const int xc0 = min(max(x0, 0), WW - 1);
      const int xc1 = min(max(x0 + 1, 0), WW - 1);
      const int yc0 = min(max(y0, 0), HH - 1);
      const int yc1 = min(max(y0 + 1, 0), HH - 1);
      const bf16x8 q00 = *(const bf16x8*)(vbase + (size_t)(yc0 * WW + xc0) * HEAD_DIM_);
      const bf16x8 q01 = *(const bf16x8*)(vbase + (size_t)(yc0 * WW + xc1) * HEAD_DIM_);
      const bf16x8 q10 = *(const bf16x8*)(vbase + (size_t)(yc1 * WW + xc0) * HEAD_DIM_);
      const bf16x8 q11 = *(const bf16x8*)(vbase + (size_t)(yc1 * WW + xc1) * HEAD_DIM_);
#pragma unroll
      for (int jj = 0; jj < 8; ++jj) {
        acc[jj] += w00 * bf2f(q00[jj]) + w01 * bf2f(q01[jj]) +
                   w10 * bf2f(q10[jj]) + w11 * bf2f(q11[jj]);
      }
    }
  }
  float* o = tmp + (size_t)row * 256 + h * 32 + c8 * 8;
  f32x4 o0 = {acc[0], acc[1], acc[2], acc[3]};
  f32x4 o1 = {acc[4], acc[5], acc[6], acc[7]};
  *(f32x4*)(o) = o0;
  *(f32x4*)(o + 4) = o1;
}

// ---------------------------------------------------------------------------
extern "C" void kernel_launch(void* const* d_in, const int* in_sizes, int n_in,
                              void* d_out, int out_size, void* d_ws, size_t ws_size,
                              hipStream_t stream) {
  const float* query  = (const float*)d_in[0];
  const float* refpts = (const float*)d_in[1];
  const float* value  = (const float*)d_in[2];
  const float* W_off  = (const float*)d_in[4];
  const float* b_off  = (const float*)d_in[5];
  const float* W_attn = (const float*)d_in[6];
  const float* b_attn = (const float*)d_in[7];
  const float* W_val  = (const float*)d_in[8];
  const float* b_val  = (const float*)d_in[9];
  const float* W_out  = (const float*)d_in[10];
  const float* b_out  = (const float*)d_in[11];
  float* out = (float*)d_out;

  // Dedicated workspace slots -- no aliasing. Total 242.7 MB.
  char* ws = (char*)d_ws;
  short* value_p = (short*)ws;                                 // 217,710,592 B
  size_t off = (size_t)BS_ * HEADS_ * LV_ * HEAD_DIM_ * 2;
  float* offsets = (float*)(ws + off); off += (size_t)BS_ * LQ_ * 256 * 4;  // 9.83 MB
  float* logits  = (float*)(ws + off); off += (size_t)BS_ * LQ_ * 128 * 4;  // 4.92 MB
  float* tmp     = (float*)(ws + off); off += (size_t)BS_ * LQ_ * 256 * 4;  // 9.83 MB
  short* WtQ = (short*)(ws + off); off += 384 * 256 * 2;                    // 192 KB
  short* WtV = (short*)(ws + off); off += 256 * 256 * 2;                    // 128 KB
  short* WtO = (short*)(ws + off); off += 256 * 256 * 2;                    // 128 KB

  const int MQ = BS_ * LQ_;   // 9600 = 64*150

  convert_all<<<896, 256, 0, stream>>>(W_off, W_attn, W_val, W_out, WtQ, WtV, WtO);
  mega_gemm<<<PSTRIDE_, 512, 0, stream>>>(value, WtV, b_val, value_p,
                                          query, WtQ, b_off, b_attn, offsets, logits);
  msda_sample_fused<<<(MQ * 32) / 256, 256, 0, stream>>>(refpts, offsets, logits, value_p, tmp);
  gemm_qproj<<<MQ / 64, 256, 0, stream>>>(tmp, WtO, b_out, out);
}

// Round 14
// 206.007 us; speedup vs baseline: 1.0417x; 1.0023x over previous
//
#include <hip/hip_runtime.h>
#include <hip/hip_bf16.h>

// Problem constants
#define BS_   32
#define LQ_   300
#define LV_   13294
#define EMBED_ 256
#define HEADS_ 8
#define HEAD_DIM_ 32
#define NCHUNK_ 13294   /* 425408 rows / 32 rows per chunk */
#define PSTRIDE_ 512    /* persistent grid size */

typedef __attribute__((ext_vector_type(8))) short bf16x8;
typedef __attribute__((ext_vector_type(4))) float f32x4;

__device__ inline short f2bf(float f) {   // RNE fp32->bf16 (bit trick)
  union { float f; unsigned u; } x; x.f = f;
  return (short)((x.u + 0x7FFF + ((x.u >> 16) & 1)) >> 16);
}
__device__ inline short f2bf_i(float f) { // via HW cvt
  union { __hip_bfloat16 h; short s; } u;
  u.h = __float2bfloat16(f);
  return u.s;
}
__device__ inline float bf2f(short s) {
  union { unsigned u; float f; } x; x.u = ((unsigned)(unsigned short)s) << 16;
  return x.f;
}

// async global->LDS, 16B per lane. LDS dest = wave-uniform base + lane*16.
__device__ __forceinline__ void gld_lds16(const void* g, void* l) {
  __builtin_amdgcn_global_load_lds(
      (const __attribute__((address_space(1))) unsigned int*)g,
      (__attribute__((address_space(3))) unsigned int*)l, 16, 0, 0);
}

// ---------------------------------------------------------------------------
// One up-front transpose+convert for ALL weights (dedicated ws slots).
// ---------------------------------------------------------------------------
__global__ void convert_all(const float* __restrict__ W_off,
                            const float* __restrict__ W_attn,
                            const float* __restrict__ W_val,
                            const float* __restrict__ W_out,
                            short* __restrict__ WtQ,
                            short* __restrict__ WtV,
                            short* __restrict__ WtO) {
  const int n = blockIdx.x;
  const int k = threadIdx.x;
  if (n < 384) {
    WtQ[n * 256 + k] = (n < 256) ? f2bf(W_off[k * 256 + n])
                                 : f2bf(W_attn[k * 128 + (n - 256)]);
  } else if (n < 640) {
    WtV[(n - 384) * 256 + k] = f2bf(W_val[k * 256 + (n - 384)]);
  } else {
    WtO[(n - 640) * 256 + k] = f2bf(W_out[k * 256 + (n - 640)]);
  }
}

// ---------------------------------------------------------------------------
// Mega GEMM: 512 blocks x 256 thr (4 waves), launch_bounds(256,2).
// RATIONALE vs R11 (8 waves x 32 cols): value phase was at the LDS-read
// roofline -- each staged A-byte re-read by 8 waves = 82 B/cyc demand vs
// the ~85 B/cyc ds_read_b128 ceiling (m134). 4 waves x 64 cols halves
// amplification to 41 B/cyc; HBM becomes the sole limiter. B slice per
// wave = bfr[4][8] = 128 VGPR (same register structure gemm_qproj has
// compiled cleanly all session under launch_bounds(256,2)).
// Phase 1 (blocks 0..149 offsets cols 0..255; blocks 150..299 logits
//   cols 256..383, 2 active waves): query tile staged to LDS, B frags
//   per-use from L2-resident WtQ.
// Phase 2 (ALL blocks): persistent value GEMM, 32-row chunks, 2 x 32 KB
//   LDS ring, counted vmcnt: stage=8 ops/wave, stores=32/wave ->
//   end-of-iter vmcnt(32) retires stage(i+1), stores stay in flight.
// ---------------------------------------------------------------------------
__global__ __launch_bounds__(256, 2) void mega_gemm(
    const float* __restrict__ value, const short* __restrict__ WtV,
    const float* __restrict__ b_val, short* __restrict__ Vp,
    const float* __restrict__ query, const short* __restrict__ WtQ,
    const float* __restrict__ b_off, const float* __restrict__ b_attn,
    float* __restrict__ offs, float* __restrict__ logits) {
  __shared__ float As[16384];   // 64 KB, shared by both phases

  const int tid = threadIdx.x;
  const int lane = tid & 63;
  const int w = tid >> 6;        // wave 0..3
  const int lr = lane & 15;
  const int lkq = lane >> 4;     // k-quarter
  const int bid = blockIdx.x;

  // ================= phase 1: query projection (blocks 0..299) ============
  if (bid < 300) {
    const bool typeA = (bid < 150);
    const int tile = typeA ? bid : bid - 150;
    const size_t m0 = (size_t)tile * 64;
    // stage query tile 64x256: 4 waves x 16 rows (1 KB per instr)
#pragma unroll
    for (int i = 0; i < 16; ++i) {
      const int row = w * 16 + i;
      gld_lds16(query + (m0 + row) * 256 + ((lane ^ (row & 7)) * 4), As + row * 256);
    }
    __syncthreads();   // drains vmcnt(0) + barrier

    if (typeA || w < 2) {
      const int n0g = typeA ? (w * 64) : (256 + w * 64);  // global col base
      f32x4 acc[4][4];
#pragma unroll
      for (int i = 0; i < 4; ++i)
#pragma unroll
        for (int jj = 0; jj < 4; ++jj) acc[i][jj] = (f32x4){0.f, 0.f, 0.f, 0.f};

#pragma unroll
      for (int kt = 0; kt < 8; ++kt) {
        bf16x8 bq[4];
#pragma unroll
        for (int nf = 0; nf < 4; ++nf)
          bq[nf] = *(const bf16x8*)(WtQ + (size_t)(n0g + nf * 16 + lr) * 256 + kt * 32 + lkq * 8);
#pragma unroll
        for (int mf = 0; mf < 4; ++mf) {
          const int row = mf * 16 + lr;
          const int g = kt * 8 + lkq * 2;
          const f32x4 a0 = *(const f32x4*)(As + row * 256 + (((g    ) ^ (row & 7)) * 4));
          const f32x4 a1 = *(const f32x4*)(As + row * 256 + (((g + 1) ^ (row & 7)) * 4));
          bf16x8 af;
#pragma unroll
          for (int i = 0; i < 4; ++i) {
            af[i]     = f2bf_i(a0[i]);
            af[i + 4] = f2bf_i(a1[i]);
          }
#pragma unroll
          for (int nf = 0; nf < 4; ++nf)
            acc[mf][nf] = __builtin_amdgcn_mfma_f32_16x16x32_bf16(af, bq[nf], acc[mf][nf], 0, 0, 0);
        }
      }

      float bvq[4];
#pragma unroll
      for (int nf = 0; nf < 4; ++nf) {
        const int n = n0g + nf * 16 + lr;
        bvq[nf] = (n < 256) ? b_off[n] : b_attn[n - 256];
      }
      const int lq4 = lkq * 4;
#pragma unroll
      for (int mf = 0; mf < 4; ++mf)
#pragma unroll
        for (int r = 0; r < 4; ++r) {
          const size_t m = m0 + mf * 16 + lq4 + r;
#pragma unroll
          for (int nf = 0; nf < 4; ++nf) {
            const int n = n0g + nf * 16 + lr;
            const float v = acc[mf][nf][r] + bvq[nf];
            if (n < 256) offs[m * 256 + n] = v;
            else         logits[m * 128 + (n - 256)] = v;
          }
        }
    }
    __syncthreads();   // all waves done with As before phase 2 overwrites it
  }

  // ================= phase 2: persistent value GEMM (all blocks) ==========
  // wave w owns cols w*64 .. +63 (heads 2w, 2w+1)
  bf16x8 bfr[4][8];
#pragma unroll
  for (int nf = 0; nf < 4; ++nf) {
    const size_t bbase = (size_t)(w * 64 + nf * 16 + lr) * 256 + lkq * 8;
#pragma unroll
    for (int kt = 0; kt < 8; ++kt)
      bfr[nf][kt] = *(const bf16x8*)(WtV + bbase + kt * 32);
  }
  float bv[4];
#pragma unroll
  for (int nf = 0; nf < 4; ++nf) bv[nf] = b_val[w * 64 + nf * 16 + lr];

  // stage one 32-row chunk (32 KB): 8 rows per wave, 1 KB per instr
  auto stage = [&](int buf, int c) {
    const float* src = value + (size_t)c * (32 * 256);
#pragma unroll
    for (int i = 0; i < 8; ++i) {
      const int r = w * 8 + i;
      gld_lds16(src + r * 256 + ((lane ^ (r & 7)) * 4), As + buf * 8192 + r * 256);
    }
  };

  const int c0 = bid;
  stage(0, c0);
  asm volatile("s_waitcnt vmcnt(0)" ::: "memory");
  __syncthreads();

  int cb = 0;
  for (int c = c0; c < NCHUNK_; c += PSTRIDE_) {
    const int nxt = c + PSTRIDE_;
    if (nxt < NCHUNK_) stage(cb ^ 1, nxt);

    f32x4 acc[2][4];
#pragma unroll
    for (int i = 0; i < 2; ++i)
#pragma unroll
      for (int jj = 0; jj < 4; ++jj) acc[i][jj] = (f32x4){0.f, 0.f, 0.f, 0.f};

    const float* as = As + cb * 8192;
#pragma unroll
    for (int kt = 0; kt < 8; ++kt) {
      const int r0 = lr;
      const int r1 = 16 + lr;
      const int g = kt * 8 + lkq * 2;
      const f32x4 a00 = *(const f32x4*)(as + r0 * 256 + (((g    ) ^ (r0 & 7)) * 4));
      const f32x4 a01 = *(const f32x4*)(as + r0 * 256 + (((g + 1) ^ (r0 & 7)) * 4));
      const f32x4 a10 = *(const f32x4*)(as + r1 * 256 + (((g    ) ^ (r1 & 7)) * 4));
      const f32x4 a11 = *(const f32x4*)(as + r1 * 256 + (((g + 1) ^ (r1 & 7)) * 4));
      bf16x8 af0, af1;
#pragma unroll
      for (int i = 0; i < 4; ++i) {
        af0[i]     = f2bf_i(a00[i]);
        af0[i + 4] = f2bf_i(a01[i]);
        af1[i]     = f2bf_i(a10[i]);
        af1[i + 4] = f2bf_i(a11[i]);
      }
#pragma unroll
      for (int nf = 0; nf < 4; ++nf) {
        acc[0][nf] = __builtin_amdgcn_mfma_f32_16x16x32_bf16(af0, bfr[nf][kt], acc[0][nf], 0, 0, 0);
        acc[1][nf] = __builtin_amdgcn_mfma_f32_16x16x32_bf16(af1, bfr[nf][kt], acc[1][nf], 0, 0, 0);
      }
    }

    // stores: wave covers heads 2w (nf 0,1) and 2w+1 (nf 2,3)
#pragma unroll
    for (int mf = 0; mf < 2; ++mf)
#pragma unroll
      for (int rr = 0; rr < 4; ++rr) {
        const unsigned m = (unsigned)c * 32 + mf * 16 + lkq * 4 + rr;
        const unsigned b_ = m / LV_;
        const unsigned pos = m - b_ * LV_;
        const size_t rb0 = ((size_t)(b_ * HEADS_ + 2 * w) * LV_ + pos) * HEAD_DIM_;
        const size_t rb1 = rb0 + (size_t)LV_ * HEAD_DIM_;
        Vp[rb0 + lr]      = f2bf(acc[mf][0][rr] + bv[0]);
        Vp[rb0 + 16 + lr] = f2bf(acc[mf][1][rr] + bv[1]);
        Vp[rb1 + lr]      = f2bf(acc[mf][2][rr] + bv[2]);
        Vp[rb1 + 16 + lr] = f2bf(acc[mf][3][rr] + bv[3]);
      }

    if (nxt < NCHUNK_) {
      asm volatile("s_waitcnt vmcnt(32)" ::: "memory");  // stage(i+1) landed
      asm volatile("s_barrier" ::: "memory");
    }
    cb ^= 1;
  }
}

// ---------------------------------------------------------------------------
// Final output projection (R6 bigA structure, f32 out).
// ---------------------------------------------------------------------------
__global__ __launch_bounds__(256, 2) void gemm_qproj(
    const float* __restrict__ A, const short* __restrict__ Wt,
    const float* __restrict__ bias, float* __restrict__ C) {
  __shared__ float As[64 * 256];

  const int tid = threadIdx.x;
  const int lane = tid & 63;
  const int w = tid >> 6;
  const int n0 = w * 64;
  const size_t m0 = (size_t)blockIdx.x * 64;
  const int lr = lane & 15;
  const int lkq = lane >> 4;

#pragma unroll
  for (int i = 0; i < 16; ++i) {
    const int row = w * 16 + i;
    gld_lds16(A + (m0 + row) * 256 + ((lane ^ (row & 7)) * 4), As + row * 256);
  }

  bf16x8 bfr[4][8];
#pragma unroll
  for (int nf = 0; nf < 4; ++nf) {
    const size_t bbase = (size_t)(n0 + nf * 16 + lr) * 256 + lkq * 8;
#pragma unroll
    for (int kt = 0; kt < 8; ++kt)
      bfr[nf][kt] = *(const bf16x8*)(Wt + bbase + kt * 32);
  }

  f32x4 acc[4][4];
#pragma unroll
  for (int i = 0; i < 4; ++i)
#pragma unroll
    for (int jj = 0; jj < 4; ++jj) acc[i][jj] = (f32x4){0.f, 0.f, 0.f, 0.f};

  __syncthreads();

#pragma unroll
  for (int kt = 0; kt < 8; ++kt) {
#pragma unroll
    for (int mf = 0; mf < 4; ++mf) {
      const int row = mf * 16 + lr;
      const int gbase = kt * 8 + lkq * 2;
      const f32x4 a0 = *(const f32x4*)(As + row * 256 + ((gbase) ^ (row & 7)) * 4);
      const f32x4 a1 = *(const f32x4*)(As + row * 256 + ((gbase + 1) ^ (row & 7)) * 4);
      bf16x8 af;
#pragma unroll
      for (int i = 0; i < 4; ++i) {
        af[i]     = f2bf_i(a0[i]);
        af[i + 4] = f2bf_i(a1[i]);
      }
#pragma unroll
      for (int nf = 0; nf < 4; ++nf)
        acc[mf][nf] = __builtin_amdgcn_mfma_f32_16x16x32_bf16(af, bfr[nf][kt], acc[mf][nf], 0, 0, 0);
    }
  }

  float bv[4];
#pragma unroll
  for (int nf = 0; nf < 4; ++nf) bv[nf] = bias[n0 + nf * 16 + lr];
  const int lq4 = lkq * 4;
#pragma unroll
  for (int mf = 0; mf < 4; ++mf)
#pragma unroll
    for (int r = 0; r < 4; ++r) {
      const size_t m = m0 + mf * 16 + lq4 + r;
#pragma unroll
      for (int nf = 0; nf < 4; ++nf) {
        const int n = n0 + nf * 16 + lr;
        C[m * 256 + n] = acc[mf][nf][r] + bv[nf];
      }
    }
}

// ---------------------------------------------------------------------------
// Fused softmax + deformable sampling, 8-channel threads (max TLP).
// ---------------------------------------------------------------------------
__global__ __launch_bounds__(256) void msda_sample_fused(
    const float* __restrict__ ref_pts,   // [BS*LQ, 4, 2]
    const float* __restrict__ offsets,   // [BS*LQ, 256]  (h,l,p,2)
    const float* __restrict__ logits,    // [BS*LQ, 128]  (h,l,p)
    const short* __restrict__ value_p,   // [b,h,pos,32] bf16
    float* __restrict__ tmp)             // [BS*LQ, 256]
{
  const int t = blockIdx.x * 256 + threadIdx.x;
  const int c8 = t & 3;
  const int h = (t >> 2) & 7;
  const int row = t >> 5;
  const int b = row / LQ_;

  const int HS[4] = {100, 50, 25, 13};
  const int START[4] = {0, 10000, 12500, 13125};

  // ---- softmax over 16 logits, in-register ----
  const float* lg = logits + (size_t)row * 128 + h * 16;
  float wv[16];
  float mx = -1e30f;
#pragma unroll
  for (int i = 0; i < 4; ++i) {
    const f32x4 v = *(const f32x4*)(lg + i * 4);
#pragma unroll
    for (int jj = 0; jj < 4; ++jj) { wv[i * 4 + jj] = v[jj]; mx = fmaxf(mx, v[jj]); }
  }
  float sum = 0.f;
#pragma unroll
  for (int i = 0; i < 16; ++i) { wv[i] = __expf(wv[i] - mx); sum += wv[i]; }
  const float inv = 1.0f / sum;
#pragma unroll
  for (int i = 0; i < 16; ++i) wv[i] *= inv;

  const float* offr = offsets + (size_t)row * 256 + h * 32;
  const float* refr = ref_pts + (size_t)row * 8;

  float acc[8];
#pragma unroll
  for (int jj = 0; jj < 8; ++jj) acc[jj] = 0.f;

#pragma unroll
  for (int l = 0; l < 4; ++l) {
    const int HH = HS[l];
    const int WW = HS[l];
    const float fH = (float)HH, fW = (float)WW;
    const float rx = refr[l * 2 + 0];
    const float ry = refr[l * 2 + 1];
    const short* vbase =
        value_p + ((size_t)(b * HEADS_ + h) * LV_ + START[l]) * HEAD_DIM_ + c8 * 8;
#pragma unroll
    for (int p = 0; p < 4; ++p) {
      const float ox = offr[(l * 4 + p) * 2 + 0];
      const float oy = offr[(l * 4 + p) * 2 + 1];
      const float x = (rx + ox / fW) * fW - 0.5f;
      const float y = (ry + oy / fH) * fH - 0.5f;
      const float x0f = floorf(x), y0f = floorf(y);
      const float fx = x - x0f, fy = y - y0f;
      const int x0 = (int)x0f, y0 = (int)y0f;
      const float wgt = wv[l * 4 + p];
      const float iy0 = (y0 >= 0 && y0 < HH) ? 1.f : 0.f;
      const float iy1 = (y0 + 1 >= 0 && y0 + 1 < HH) ? 1.f : 0.f;
      const float ix0 = (x0 >= 0 && x0 < WW) ? 1.f : 0.f;
      const float ix1 = (x0 + 1 >= 0 && x0 + 1 < WW) ? 1.f : 0.f;
      const float w00 = (1.f - fy) * (1.f - fx) * wgt * iy0 * ix0;
      const float w01 = (1.f - fy) * fx * wgt * iy0 * ix1;
      const float w10 = fy * (1.f - fx) * wgt * iy1 * ix0;
      const float w11 = fy * fx * wgt * iy1 * ix1;
      const int xc0 = min(max(x0, 0), WW - 1);
      const int xc1 = min(max(x0 + 1, 0), WW - 1);
      const int yc0 = min(max(y0, 0), HH - 1);
      const int yc1 = min(max(y0 + 1, 0), HH - 1);
      const bf16x8 q00 = *(const bf16x8*)(vbase + (size_t)(yc0 * WW + xc0) * HEAD_DIM_);
      const bf16x8 q01 = *(const bf16x8*)(vbase + (size_t)(yc0 * WW + xc1) * HEAD_DIM_);
      const bf16x8 q10 = *(const bf16x8*)(vbase + (size_t)(yc1 * WW + xc0) * HEAD_DIM_);
      const bf16x8 q11 = *(const bf16x8*)(vbase + (size_t)(yc1 * WW + xc1) * HEAD_DIM_);
#pragma unroll
      for (int jj = 0; jj < 8; ++jj) {
        acc[jj] += w00 * bf2f(q00[jj]) + w01 * bf2f(q01[jj]) +
                   w10 * bf2f(q10[jj]) + w11 * bf2f(q11[jj]);
      }
    }
  }
  float* o = tmp + (size_t)row * 256 + h * 32 + c8 * 8;
  f32x4 o0 = {acc[0], acc[1], acc[2], acc[3]};
  f32x4 o1 = {acc[4], acc[5], acc[6], acc[7]};
  *(f32x4*)(o) = o0;
  *(f32x4*)(o + 4) = o1;
}

// ---------------------------------------------------------------------------
extern "C" void kernel_launch(void* const* d_in, const int* in_sizes, int n_in,
                              void* d_out, int out_size, void* d_ws, size_t ws_size,
                              hipStream_t stream) {
  const float* query  = (const float*)d_in[0];
  const float* refpts = (const float*)d_in[1];
  const float* value  = (const float*)d_in[2];
  const float* W_off  = (const float*)d_in[4];
  const float* b_off  = (const float*)d_in[5];
  const float* W_attn = (const float*)d_in[6];
  const float* b_attn = (const float*)d_in[7];
  const float* W_val  = (const float*)d_in[8];
  const float* b_val  = (const float*)d_in[9];
  const float* W_out  = (const float*)d_in[10];
  const float* b_out  = (const float*)d_in[11];
  float* out = (float*)d_out;

  // Dedicated workspace slots -- no aliasing. Total 242.7 MB.
  char* ws = (char*)d_ws;
  short* value_p = (short*)ws;                                 // 217,710,592 B
  size_t off = (size_t)BS_ * HEADS_ * LV_ * HEAD_DIM_ * 2;
  float* offsets = (float*)(ws + off); off += (size_t)BS_ * LQ_ * 256 * 4;  // 9.83 MB
  float* logits  = (float*)(ws + off); off += (size_t)BS_ * LQ_ * 128 * 4;  // 4.92 MB
  float* tmp     = (float*)(ws + off); off += (size_t)BS_ * LQ_ * 256 * 4;  // 9.83 MB
  short* WtQ = (short*)(ws + off); off += 384 * 256 * 2;                    // 192 KB
  short* WtV = (short*)(ws + off); off += 256 * 256 * 2;                    // 128 KB
  short* WtO = (short*)(ws + off); off += 256 * 256 * 2;                    // 128 KB

  const int MQ = BS_ * LQ_;   // 9600 = 64*150

  convert_all<<<896, 256, 0, stream>>>(W_off, W_attn, W_val, W_out, WtQ, WtV, WtO);
  mega_gemm<<<PSTRIDE_, 256, 0, stream>>>(value, WtV, b_val, value_p,
                                          query, WtQ, b_off, b_attn, offsets, logits);
  msda_sample_fused<<<(MQ * 32) / 256, 256, 0, stream>>>(refpts, offsets, logits, value_p, tmp);
  gemm_qproj<<<MQ / 64, 256, 0, stream>>>(tmp, WtO, b_out, out);
}